// Round 6
// baseline (101.210 us; speedup 1.0000x reference)
//
#include <hip/hip_runtime.h>

// Per-channel int4-codebook quantize/dequantize, bit-exact vs the jnp reference.
// R4's PROVEN inner loop (tournament over clamped candidates {k-1,k,k+1}),
// memory schedule changed to VPT=16 / one block per row for deeper MLP.
//
// Exact structure assumed (verified): grid sorted, grid[8-i] == -grid[8+i]
// (fp negation exact), grid[8] == 0, grid[15] == max. All codebook values are
// LOADED from the input grid (never re-derived — R2 lesson).
//
// Magnitude domain: m = |xs|, tab[k] = |grid value|, k = 0..8
//   (positive side has k = 0..7 only; negative side k = 0..8).
// Reference decision (searchsorted-left + |xs-vlo| <= |xs-vhi| -> vlo):
//   |fl(xs - v)| == |fl(m - |v|)| exactly by sign symmetry. Tie -> lower VALUE:
//     xs >= 0: prefer lower k  (advance only on strict <)
//     xs <  0: prefer higher k (advance on <=)
// Guess k = rint(m/step) has rel err ~1e-6 << 0.5 index, so clamped
// candidates {k-1, k, k+1} always contain the true {floor, ceil} pair; the
// third candidate is >= one full step away and cannot win or tie.
// Dequant: dq[k] = fl(tab[k]/scale) (IEEE div); fl(-q/s) = -fl(q/s) exactly,
// so out = copysign(dq[k], xs).

typedef float f32x4 __attribute__((ext_vector_type(4)));

constexpr int TPB = 256;
constexpr int VPT = 16;  // float4 per thread -> 16384 elems = one full row/block

__global__ __launch_bounds__(TPB) void quant_kernel(
    const f32x4* __restrict__ x,
    const float* __restrict__ alpha,
    const float* __restrict__ grid,
    f32x4*       __restrict__ out)
{
    __shared__ float tabs[9];   // scaled-domain |grid| magnitudes
    __shared__ float dq[9];     // dequantized magnitudes (per-row)

    const int tid = threadIdx.x;
    const int row = blockIdx.x;

    const float g15 = grid[15];              // max grid value
    const float a = alpha[row];
    const float scale = g15 / a;             // IEEE fp32 div, matches reference
    const float inv_step = 1.0f / grid[9];   // guess only

    if (tid < 9) {
        float t = (tid < 8) ? grid[8 + tid] : -grid[0];   // exact negation
        tabs[tid] = t;
        dq[tid] = t / scale;                 // IEEE div, matches reference
    }
    __syncthreads();

    const long base = (long)row * (TPB * VPT) + tid;      // float4 index

    f32x4 v[VPT];
    #pragma unroll
    for (int i = 0; i < VPT; ++i)
        v[i] = __builtin_nontemporal_load(&x[base + (long)i * TPB]);

    #pragma unroll
    for (int i = 0; i < VPT; ++i) {
        float res[4];
        #pragma unroll
        for (int e = 0; e < 4; ++e) {
            float xs = v[i][e] * scale;
            float m  = fabsf(xs);
            bool neg = xs < 0.0f;
            int kmax = neg ? 8 : 7;          // no +8-step entry on positive side
            int ki = (int)rintf(m * inv_step);      // m >= 0 so ki >= 0
            ki = min(ki, kmax);
            int k0 = max(ki - 1, 0);
            int k2 = min(ki + 1, kmax);
            float t0 = tabs[k0], t1 = tabs[ki], t2 = tabs[k2];
            float d0 = fabsf(m - t0);        // == |fl(xs - vlo/vhi)| bit-exact
            float d1 = fabsf(m - t1);
            float d2 = fabsf(m - t2);
            // tournament, tie rule folded in:
            bool up1 = neg ? (d1 <= d0) : (d1 < d0);
            int   bk = up1 ? ki : k0;
            float bd = up1 ? d1 : d0;
            bool up2 = neg ? (d2 <= bd) : (d2 < bd);
            bk = up2 ? k2 : bk;
            float q = dq[bk];                // 9 words -> 9 banks, broadcast
            res[e] = __builtin_copysignf(q, xs);
        }
        f32x4 o; o[0] = res[0]; o[1] = res[1]; o[2] = res[2]; o[3] = res[3];
        __builtin_nontemporal_store(o, &out[base + (long)i * TPB]);
    }
}

extern "C" void kernel_launch(void* const* d_in, const int* in_sizes, int n_in,
                              void* d_out, int out_size, void* d_ws, size_t ws_size,
                              hipStream_t stream) {
    const float* x     = (const float*)d_in[0];   // [C, F] fp32
    const float* alpha = (const float*)d_in[1];   // [C, 1] fp32
    const float* grid  = (const float*)d_in[2];   // [16] fp32, sorted
    float* out = (float*)d_out;

    int total = in_sizes[0];          // C*F = 67,108,864
    int C     = in_sizes[1];          // 4096  -> one block per row
    (void)total;

    quant_kernel<<<C, TPB, 0, stream>>>(
        (const f32x4*)x, alpha, grid, (f32x4*)out);
}

// Round 7
// 93.191 us; speedup vs baseline: 1.0860x; 1.0860x over previous
//
#include <hip/hip_runtime.h>

// Per-channel int4-codebook quantize/dequantize, bit-exact vs the jnp reference.
// == R4 kernel, verbatim (best measured: 93.4 us, 5.75 TB/s, absmax 0.0). ==
// R5 (threshold-bisection, fewer VALU) -> 96.6 us; R6 (VPT=16 deep ILP) ->
// 101.2 us. Both regressed: the kernel is BW-bound at ~91% of the float4-copy
// ceiling; inner-loop arithmetic and per-thread ILP are not the limiter.
//
// Exact structure assumed (verified): grid sorted, grid[8-i] == -grid[8+i]
// (fp negation exact), grid[8] == 0, grid[15] == max. All codebook values are
// LOADED from the input grid (never re-derived — R2 lesson).
//
// Magnitude domain: m = |xs|, tab[k] = |grid value|, k = 0..8
//   (positive side has k = 0..7 only; negative side k = 0..8).
// Reference decision (searchsorted-left + |xs-vlo| <= |xs-vhi| -> vlo):
//   |fl(xs - v)| == |fl(m - |v|)| exactly by sign symmetry. Tie -> lower VALUE:
//     xs >= 0: prefer lower k  (advance only on strict <)
//     xs <  0: prefer higher k (advance on <=)
// Guess k = rint(m/step) has rel err ~1e-6 << 0.5 index, so clamped
// candidates {k-1, k, k+1} always contain the true {floor, ceil} pair; the
// third candidate is >= one full step away and cannot win or tie.
// Dequant: dq[k] = fl(tab[k]/scale) (IEEE div); fl(-q/s) = -fl(q/s) exactly,
// so out = copysign(dq[k], xs).

typedef float f32x4 __attribute__((ext_vector_type(4)));

constexpr int TPB = 256;
constexpr int VPT = 8;   // float4 per thread -> 8192 elements per block

__global__ __launch_bounds__(TPB) void quant_kernel(
    const f32x4* __restrict__ x,
    const float* __restrict__ alpha,
    const float* __restrict__ grid,
    f32x4*       __restrict__ out,
    int rowShift)            // log2(blocks per row)
{
    __shared__ float tabs[9];   // scaled-domain |grid| magnitudes
    __shared__ float dq[9];     // dequantized magnitudes (per-row)

    const int tid = threadIdx.x;
    const int bid = blockIdx.x;
    const int row = bid >> rowShift;

    const float g15 = grid[15];              // max grid value
    const float a = alpha[row];
    const float scale = g15 / a;             // IEEE fp32 div, matches reference
    const float inv_step = 1.0f / grid[9];   // guess only

    if (tid < 9) {
        float t = (tid < 8) ? grid[8 + tid] : -grid[0];   // exact negation
        tabs[tid] = t;
        dq[tid] = t / scale;                 // IEEE div, matches reference
    }
    __syncthreads();

    const long base = (long)bid * (TPB * VPT) + tid;      // float4 index

    f32x4 v[VPT];
    #pragma unroll
    for (int i = 0; i < VPT; ++i)
        v[i] = __builtin_nontemporal_load(&x[base + (long)i * TPB]);

    #pragma unroll
    for (int i = 0; i < VPT; ++i) {
        float res[4];
        #pragma unroll
        for (int e = 0; e < 4; ++e) {
            float xs = v[i][e] * scale;
            float m  = fabsf(xs);
            bool neg = xs < 0.0f;
            int kmax = neg ? 8 : 7;          // no +8-step entry on positive side
            int ki = (int)rintf(m * inv_step);      // m >= 0 so ki >= 0
            ki = min(ki, kmax);
            int k0 = max(ki - 1, 0);
            int k2 = min(ki + 1, kmax);
            float t0 = tabs[k0], t1 = tabs[ki], t2 = tabs[k2];
            float d0 = fabsf(m - t0);        // == |fl(xs - vlo/vhi)| bit-exact
            float d1 = fabsf(m - t1);
            float d2 = fabsf(m - t2);
            // tournament, tie rule folded in:
            bool up1 = neg ? (d1 <= d0) : (d1 < d0);
            int   bk = up1 ? ki : k0;
            float bd = up1 ? d1 : d0;
            bool up2 = neg ? (d2 <= bd) : (d2 < bd);
            bk = up2 ? k2 : bk;
            float q = dq[bk];                // 9 words -> 9 banks, broadcast
            res[e] = __builtin_copysignf(q, xs);
        }
        f32x4 o; o[0] = res[0]; o[1] = res[1]; o[2] = res[2]; o[3] = res[3];
        __builtin_nontemporal_store(o, &out[base + (long)i * TPB]);
    }
}

extern "C" void kernel_launch(void* const* d_in, const int* in_sizes, int n_in,
                              void* d_out, int out_size, void* d_ws, size_t ws_size,
                              hipStream_t stream) {
    const float* x     = (const float*)d_in[0];   // [C, F] fp32
    const float* alpha = (const float*)d_in[1];   // [C, 1] fp32
    const float* grid  = (const float*)d_in[2];   // [16] fp32, sorted
    float* out = (float*)d_out;

    int total = in_sizes[0];          // C*F = 67,108,864
    int C     = in_sizes[1];          // 4096
    int F     = total / C;            // 16384
    int vec4PerRow   = F / 4;         // 4096
    int vec4PerBlock = TPB * VPT;     // 2048
    int blocksPerRow = vec4PerRow / vec4PerBlock;   // 2
    int rowShift = 0;
    while ((1 << rowShift) < blocksPerRow) ++rowShift;  // = 1

    int blocks = C * blocksPerRow;    // 8192
    quant_kernel<<<blocks, TPB, 0, stream>>>(
        (const f32x4*)x, alpha, grid, (f32x4*)out, rowShift);
}